// Round 7
// baseline (239.722 us; speedup 1.0000x reference)
//
#include <hip/hip_runtime.h>
#include <math.h>

#define M_ 3
#define B_ 64
#define D_ 512
#define H4 128     // D/4
#define HIST_ 5
#define BD (B_ * D_)        // 32768
#define INVSCALE 0.04419417382415922f   // 1/sqrt(512)
#define LOG2E 1.4426950408889634f

__device__ __forceinline__ float wave_sum64(float v) {
#pragma unroll
    for (int o = 32; o >= 1; o >>= 1) v += __shfl_xor(v, o, 64);
    return v;
}

__device__ __forceinline__ float sigmoidf(float x) {
    return 1.0f / (1.0f + __expf(-x));
}

// ---------------------------------------------------------------------------
// k_proj v3: batch-amortized GEMM. y[m,b,d] = x[m,b,:] . pW[m,d,:] + pb.
// grid = 384 blocks = (m, 4-d chunk). 256 thr = 4 waves (wave = d-lane dl,
// lane = batch b). Per k-quarter: stage x[64][128] (pad 136: 2-way bank =
// free) + W[4][128] into LDS; lanes read xs[b] (2-way) and ws[dl]
// (broadcast). Weight bytes read ONCE grid-wide (3 MB vs 192 MB in R5/R6's
// per-(m,b) decomposition -- that kernel ran at ~4.8 TB/s effective L2
// stream, 288 MB demand = 60 us; this cuts demand ~10x).
// Quarter partials summed ((q0+q1)+q2)+q3 + pb = bit-identical to old path.
// ---------------------------------------------------------------------------
__global__ __launch_bounds__(256) void k_proj(
    const float* __restrict__ x, const float* __restrict__ pW,
    const float* __restrict__ pb, float* __restrict__ y)
{
    const int m   = blockIdx.x >> 7;       // 0..2
    const int dch = blockIdx.x & 127;      // 0..127
    const int d0  = dch << 2;
    const int t   = threadIdx.x;
    const int dl  = t >> 6;                // wave id 0..3 -> d = d0+dl
    const int bl  = t & 63;                // lane = batch

    __shared__ __align__(16) float xs[64][136];
    __shared__ __align__(16) float ws4[4][128];

    const float* xbase = x + (size_t)m * BD;
    float part[4];

#pragma unroll
    for (int q = 0; q < 4; ++q) {
        // stage x tile: 64 b x 128 k = 2048 float4, coalesced
#pragma unroll
        for (int j = 0; j < 8; ++j) {
            const int f  = t + (j << 8);
            const int b  = f >> 5;
            const int c4 = f & 31;
            const float4 v = *(const float4*)(xbase + (size_t)b * D_ + (q << 7) + (c4 << 2));
            *(float4*)(&xs[b][c4 << 2]) = v;
        }
        // stage 4 weight rows: 128 float4
        if (t < 128) {
            const int r  = t >> 5;
            const int c4 = t & 31;
            *(float4*)(&ws4[r][c4 << 2]) =
                *(const float4*)(pW + ((size_t)m * D_ + d0 + r) * D_ + (q << 7) + (c4 << 2));
        }
        __syncthreads();

        float acc = 0.f;
#pragma unroll
        for (int c4 = 0; c4 < 32; ++c4) {
            const float4 w = *(const float4*)(&ws4[dl][c4 << 2]);
            const float4 a = *(const float4*)(&xs[bl][c4 << 2]);
            acc = fmaf(w.x, a.x, acc); acc = fmaf(w.y, a.y, acc);
            acc = fmaf(w.z, a.z, acc); acc = fmaf(w.w, a.w, acc);
        }
        part[q] = acc;
        __syncthreads();
    }

    const float yv = ((part[0] + part[1]) + part[2]) + part[3] + pb[m * D_ + d0 + dl];
    y[(size_t)(m * B_ + bl) * D_ + d0 + dl] = yv;
}

// ---------------------------------------------------------------------------
// k_lnmlp: per (m,b) row -- LayerNorm+ReLU, MLP1 (4-way K-split), MLP2,
// wf = p*sigmoid, Ssum. (R0-proven body; input y instead of ypart quarters;
// no atomics -- k_pass stores out.) Block 0 writes attention weights.
// grid = 192 blocks, 512 threads (thread = d).
// ---------------------------------------------------------------------------
__global__ __launch_bounds__(512) void k_lnmlp(
    const float* __restrict__ y, const float* __restrict__ lg,
    const float* __restrict__ lb, const float* __restrict__ W1,
    const float* __restrict__ b1, const float* __restrict__ W2,
    const float* __restrict__ b2, const float* __restrict__ gamma,
    float* __restrict__ wf, float* __restrict__ Ssum,
    float* __restrict__ out)
{
    const int m = blockIdx.x >> 6;
    const int b = blockIdx.x & 63;
    const int t = threadIdx.x;
    __shared__ __align__(16) float ps[D_];
    __shared__ __align__(16) float hs[H4];
    __shared__ __align__(16) float hpart[512];
    __shared__ float red[8];

    const float yv = y[(size_t)(m * B_ + b) * D_ + t];

    float s = wave_sum64(yv);
    if ((t & 63) == 0) red[t >> 6] = s;
    __syncthreads();
    const float mean = (red[0]+red[1]+red[2]+red[3]+red[4]+red[5]+red[6]+red[7]) * (1.f / D_);
    __syncthreads();
    const float v = yv - mean;
    float vs = wave_sum64(v * v);
    if ((t & 63) == 0) red[t >> 6] = vs;
    __syncthreads();
    const float inv = rsqrtf((red[0]+red[1]+red[2]+red[3]+red[4]+red[5]+red[6]+red[7]) * (1.f / D_) + 1e-5f);
    const float p = fmaxf(fmaf(v * inv, lg[m * D_ + t], lb[m * D_ + t]), 0.f);
    ps[t] = p;
    __syncthreads();

    // MLP1: thread -> (r = t&127, seg = t>>7)
    {
        const int r = t & 127, seg = t >> 7;
        const float4* w1 = (const float4*)(W1 + ((size_t)m * H4 + r) * D_) + (seg << 5);
        const float4* pv = (const float4*)ps + (seg << 5);
        float a1 = 0.f;
#pragma unroll
        for (int k = 0; k < 32; ++k) {
            const float4 w = w1[k], pp = pv[k];
            a1 = fmaf(w.x, pp.x, a1); a1 = fmaf(w.y, pp.y, a1);
            a1 = fmaf(w.z, pp.z, a1); a1 = fmaf(w.w, pp.w, a1);
        }
        hpart[t] = a1;
    }
    __syncthreads();
    if (t < H4)
        hs[t] = fmaxf(hpart[t] + hpart[t + 128] + hpart[t + 256] + hpart[t + 384]
                      + b1[m * H4 + t], 0.f);
    __syncthreads();

    // MLP2
    const float4* w2 = (const float4*)(W2 + ((size_t)m * D_ + t) * H4);
    const float4* hv = (const float4*)hs;
    float a2 = 0.f;
#pragma unroll
    for (int k = 0; k < H4 / 4; ++k) {
        const float4 w = w2[k], hh = hv[k];
        a2 = fmaf(w.x, hh.x, a2); a2 = fmaf(w.y, hh.y, a2);
        a2 = fmaf(w.z, hh.z, a2); a2 = fmaf(w.w, hh.w, a2);
    }
    const float cw = sigmoidf(a2 + b2[m * D_ + t]);
    const float wv = p * cw;
    wf[(size_t)(m * B_ + b) * D_ + t] = wv;

    float tot = wave_sum64(wv);
    if ((t & 63) == 0) red[t >> 6] = tot;
    __syncthreads();
    if (t == 0)
        Ssum[m * B_ + b] = red[0]+red[1]+red[2]+red[3]+red[4]+red[5]+red[6]+red[7];

    if (blockIdx.x == 0 && t == 0) {
        const float g01 = sigmoidf(gamma[1]), g02 = sigmoidf(gamma[2]);
        const float g10 = sigmoidf(gamma[3]), g12 = sigmoidf(gamma[5]);
        const float g20 = sigmoidf(gamma[6]), g21 = sigmoidf(gamma[7]);
        const float s0 = 0.5f * (g01 + g02);
        const float s1 = 0.5f * (g10 + g12);
        const float s2 = 0.5f * (g20 + g21);
        const float mx = fmaxf(s0, fmaxf(s1, s2));
        const float e0 = __expf(s0 - mx), e1 = __expf(s1 - mx), e2 = __expf(s2 - mx);
        const float den = e0 + e1 + e2;
        out[BD + 0] = e0 / den;
        out[BD + 1] = e1 / den;
        out[BD + 2] = e2 / den;
    }
}

// ---------------------------------------------------------------------------
// k_hist: history matrices, TRANSPOSED HT[i][e][d] pre-scaled by LOG2E.
// grid = 384 blocks: block=(i, e-quad), thread = d & d+256.
// ---------------------------------------------------------------------------
__global__ __launch_bounds__(256) void k_hist(
    const float* __restrict__ wf, const float* __restrict__ cons,
    float* __restrict__ HT)
{
    const int t  = threadIdx.x;
    const int i  = blockIdx.x >> 7;         // 128 blocks per mode
    const int e0 = (blockIdx.x & 127) << 2;
    const int j  = (i == 0) ? 1 : 0;
    const float c = cons[i];
    const float* wfi = wf + (size_t)i * BD;
    const float* wfj = wf + (size_t)j * BD;

    float h0[4] = {0.f, 0.f, 0.f, 0.f};
    float h1[4] = {0.f, 0.f, 0.f, 0.f};
#pragma unroll 2
    for (int b = 0; b < B_; ++b) {
        const float a0 = wfi[b * D_ + t]       * INVSCALE;
        const float a1 = wfi[b * D_ + t + 256] * INVSCALE;
        const float4 u4 = *(const float4*)(wfj + b * D_ + e0);
        const float uu[4] = {u4.x, u4.y, u4.z, u4.w};
#pragma unroll
        for (int k = 0; k < 4; ++k) {
            float tt = a0 * uu[k]; float mm = fminf(tt, c);
            h0[k] = fmaf(0.8f, mm, fmaf(0.2f, tt, h0[k]));
            tt = a1 * uu[k]; mm = fminf(tt, c);
            h1[k] = fmaf(0.8f, mm, fmaf(0.2f, tt, h1[k]));
        }
    }
    const float hsc = LOG2E / (float)(B_ * HIST_);
    float* r0 = HT + ((size_t)(i << 9) + e0) * D_;
#pragma unroll
    for (int k = 0; k < 4; ++k) {
        r0[(size_t)k * D_ + t]       = h0[k] * hsc;
        r0[(size_t)k * D_ + t + 256] = h1[k] * hsc;
    }
}

// ---------------------------------------------------------------------------
// k_pass: all 6 (i,j) softmax-dot passes per block, 4 batches per block
// (halves HT re-read vs 2-batch). grid = 256 blocks: block=(b-quad, 32-d
// chunk), 256 thr = 32 d x 8 e-secs. Single non-atomic store:
// out[b,d] = sum(pv)/6 + (wf0+wf1+wf2)/3.
// ---------------------------------------------------------------------------
__global__ __launch_bounds__(256) void k_pass(
    const float* __restrict__ wf, const float* __restrict__ cons,
    const float* __restrict__ gamma, const float* __restrict__ mbias,
    const float* __restrict__ HT, const float* __restrict__ Ssum,
    float* __restrict__ out)
{
    const int bg   = blockIdx.x >> 4;       // 0..15 (b-quad)
    const int dc   = blockIdx.x & 15;
    const int b0   = bg << 2;
    const int t    = threadIdx.x;
    const int ln   = t & 31;
    const int d    = (dc << 5) + ln;
    const int esec = t >> 5;                // 0..7, 64 e's each

    __shared__ __align__(16) float4 part[4][256];
    float oacc = 0.f;                        // used by t<128

#pragma unroll
    for (int i = 0; i < 3; ++i) {
        const int jA = (i == 0) ? 1 : 0;
        const int jB = (i == 2) ? 1 : 2;
        const float c08 = cons[i] * (0.8f * LOG2E);
        const float cl  = cons[i] * LOG2E;

        float a08[4], a02[4], aB[4];
        const float* uA[4];
        const float* uB[4];
#pragma unroll
        for (int bb = 0; bb < 4; ++bb) {
            const float a = wf[(size_t)i * BD + (b0 + bb) * D_ + d];
            a08[bb] = a * (0.8f * INVSCALE * LOG2E);
            a02[bb] = a * (0.2f * INVSCALE * LOG2E);
            aB[bb]  = a * (INVSCALE * LOG2E);
            uA[bb] = wf + (size_t)jA * BD + (b0 + bb) * D_ + (esec << 6);
            uB[bb] = wf + (size_t)jB * BD + (b0 + bb) * D_ + (esec << 6);
        }
        const float* hp = HT + ((size_t)(i << 9) + (esec << 6)) * D_ + d;

        float sA[4] = {0.f, 0.f, 0.f, 0.f}, dA[4] = {0.f, 0.f, 0.f, 0.f};
        float sB[4] = {0.f, 0.f, 0.f, 0.f}, dB[4] = {0.f, 0.f, 0.f, 0.f};
#pragma unroll 2
        for (int e = 0; e < 64; e += 4) {
            float hh[4];
#pragma unroll
            for (int k = 0; k < 4; ++k) hh[k] = hp[(size_t)(e + k) * D_];
#pragma unroll
            for (int bb = 0; bb < 4; ++bb) {
                const float4 uA4 = *(const float4*)(uA[bb] + e);
                const float4 uB4 = *(const float4*)(uB[bb] + e);
                const float ua[4] = {uA4.x, uA4.y, uA4.z, uA4.w};
                const float ub[4] = {uB4.x, uB4.y, uB4.z, uB4.w};
#pragma unroll
                for (int k = 0; k < 4; ++k) {
                    // pass A (hist = 0): f = min(a08*u, c08) + a02*u
                    const float v1 = a08[bb] * ua[k];
                    const float v2 = fminf(v1, c08);
                    const float fA = fmaf(a02[bb], ua[k], v2);
                    const float pA = __builtin_amdgcn_exp2f(fA);
                    sA[bb] += pA;
                    dA[bb] = fmaf(pA, ua[k], dA[bb]);
                    // pass B: f = 0.8*(h + clip(a*u - h)) + 0.2*a*u
                    const float tt = aB[bb] * ub[k];
                    const float df = tt - hh[k];
                    const float mm = fminf(fmaxf(df, -cl), cl);
                    const float fB = fmaf(0.8f, hh[k] + mm, 0.2f * tt);
                    const float pB = __builtin_amdgcn_exp2f(fB);
                    sB[bb] += pB;
                    dB[bb] = fmaf(pB, ub[k], dB[bb]);
                }
            }
        }

#pragma unroll
        for (int bb = 0; bb < 4; ++bb)
            part[bb][t] = make_float4(sA[bb], dA[bb], sB[bb], dB[bb]);
        __syncthreads();
        if (t < 128) {
            const int bb = t >> 5;
            const int l  = t & 31;
            float SsA = 0.f, SdA = 0.f, SsB = 0.f, SdB = 0.f;
#pragma unroll
            for (int k = 0; k < 8; ++k) {
                const float4 pp = part[bb][l + (k << 5)];
                SsA += pp.x; SdA += pp.y; SsB += pp.z; SdB += pp.w;
            }
            const float gA = sigmoidf(gamma[i * 3 + jA]);
            const float gB = sigmoidf(gamma[i * 3 + jB]);
            oacc += gA * (SdA / SsA + mbias[i * 3 + jA] * Ssum[jA * B_ + b0 + bb]);
            oacc += gB * (SdB / SsB + mbias[i * 3 + jB] * Ssum[jB * B_ + b0 + bb]);
        }
        __syncthreads();                      // protect part reuse next i
    }

    if (t < 128) {
        const int bb = t >> 5;
        const int l  = t & 31;
        const int od = (dc << 5) + l;
        const float w0 = wf[(size_t)0 * BD + (b0 + bb) * D_ + od];
        const float w1 = wf[(size_t)1 * BD + (b0 + bb) * D_ + od];
        const float w2 = wf[(size_t)2 * BD + (b0 + bb) * D_ + od];
        out[(b0 + bb) * D_ + od] = oacc * (1.f / 6.f) + (w0 + w1 + w2) * (1.f / 3.f);
    }
}

// ---------------------------------------------------------------------------
extern "C" void kernel_launch(void* const* d_in, const int* in_sizes, int n_in,
                              void* d_out, int out_size, void* d_ws, size_t ws_size,
                              hipStream_t stream) {
    const float* x    = (const float*)d_in[0];
    const float* pW   = (const float*)d_in[1];
    const float* pb   = (const float*)d_in[2];
    const float* lg   = (const float*)d_in[3];
    const float* lb   = (const float*)d_in[4];
    const float* W1   = (const float*)d_in[5];
    const float* b1   = (const float*)d_in[6];
    const float* W2   = (const float*)d_in[7];
    const float* b2   = (const float*)d_in[8];
    const float* gamma= (const float*)d_in[9];
    const float* mb   = (const float*)d_in[10];
    const float* cons = (const float*)d_in[11];
    float* out = (float*)d_out;

    float* ws   = (float*)d_ws;
    float* wf   = ws;                 // 98304 floats
    float* Ssum = ws + 98304;         // 192
    float* HT   = ws + 98496;         // 786432 (HT[i][e][d], *LOG2E)
    float* y    = ws + 884928;        // 98304

    k_proj <<<dim3(384),     dim3(256), 0, stream>>>(x, pW, pb, y);
    k_lnmlp<<<dim3(M_ * B_), dim3(512), 0, stream>>>(y, lg, lb, W1, b1, W2, b2, gamma, wf, Ssum, out);
    k_hist <<<dim3(384),     dim3(256), 0, stream>>>(wf, cons, HT);
    k_pass <<<dim3(256),     dim3(256), 0, stream>>>(wf, cons, gamma, mb, HT, Ssum, out);
}

// Round 8
// 198.143 us; speedup vs baseline: 1.2098x; 1.2098x over previous
//
#include <hip/hip_runtime.h>
#include <math.h>

#define M_ 3
#define B_ 64
#define D_ 512
#define H4 128     // D/4
#define HIST_ 5
#define BD (B_ * D_)        // 32768
#define INVSCALE 0.04419417382415922f   // 1/sqrt(512)
#define LOG2E 1.4426950408889634f

__device__ __forceinline__ float wave_sum64(float v) {
#pragma unroll
    for (int o = 32; o >= 1; o >>= 1) v += __shfl_xor(v, o, 64);
    return v;
}

__device__ __forceinline__ float half_sum32(float v) {
#pragma unroll
    for (int o = 16; o >= 1; o >>= 1) v += __shfl_xor(v, o, 64);
    return v;
}

__device__ __forceinline__ float sigmoidf(float x) {
    return 1.0f / (1.0f + __expf(-x));
}

// ---------------------------------------------------------------------------
// k_projln v3: fused proj GEMM + LN + ReLU + MLP + wf + Ssum, COALESCED.
// grid = 192 blocks (m,b), 512 threads = 8 waves.
// R5/R6's thread-per-d mapping made every wave-load touch 64 cache lines
// (2KB apart) -> TA/TCP transaction-bound at ~60us. v3: wave-per-row --
// lane l holds x chunk k=[4l,4l+4)+[256+4l,..) IN REGISTERS; the wave walks
// its 64 rows with 1KB-contiguous loads; 6-shuffle tree reduces the dot.
// MLP1 same (wave per row, 16 rows/wave). MLP2: half-wave per row (2 rows
// per contiguous 1KB wave-load), 5-shuffle reduce.
// ---------------------------------------------------------------------------
__global__ __launch_bounds__(512) void k_projln(
    const float* __restrict__ x, const float* __restrict__ pW,
    const float* __restrict__ pb, const float* __restrict__ lg,
    const float* __restrict__ lb, const float* __restrict__ W1,
    const float* __restrict__ b1, const float* __restrict__ W2,
    const float* __restrict__ b2, const float* __restrict__ gamma,
    float* __restrict__ wf, float* __restrict__ Ssum,
    float* __restrict__ out)
{
    const int m = blockIdx.x >> 6;
    const int b = blockIdx.x & 63;
    const int t = threadIdx.x;
    const int w = t >> 6;      // wave 0..7
    const int l = t & 63;      // lane

    __shared__ __align__(16) float xs[D_];
    __shared__ __align__(16) float ys[D_];   // proj y; reused for MLP2 a2
    __shared__ __align__(16) float ps[D_];
    __shared__ __align__(16) float hs[H4];
    __shared__ float red[8];

    xs[t] = x[(size_t)(m * B_ + b) * D_ + t];
    __syncthreads();

    // ---- proj: wave w owns d = w*64 .. w*64+63; lane chunk in regs ----
    {
        const float4* xv = (const float4*)xs;
        const float4 xa = xv[l];
        const float4 xb = xv[64 + l];
        const float* wbase = pW + (size_t)m * D_ * D_;
#pragma unroll 2
        for (int dd = 0; dd < 64; ++dd) {
            const int d = (w << 6) + dd;
            const float4* wr = (const float4*)(wbase + (size_t)d * D_);
            const float4 wa = wr[l];
            const float4 wb = wr[64 + l];
            float acc;
            acc = wa.x * xa.x;            acc = fmaf(wa.y, xa.y, acc);
            acc = fmaf(wa.z, xa.z, acc);  acc = fmaf(wa.w, xa.w, acc);
            acc = fmaf(wb.x, xb.x, acc);  acc = fmaf(wb.y, xb.y, acc);
            acc = fmaf(wb.z, xb.z, acc);  acc = fmaf(wb.w, xb.w, acc);
            acc = wave_sum64(acc);
            if (l == 0) ys[d] = acc;
        }
    }
    __syncthreads();

    // ---- LayerNorm + ReLU (thread = d) ----
    const float y = ys[t] + pb[m * D_ + t];
    float s = wave_sum64(y);
    if ((t & 63) == 0) red[t >> 6] = s;
    __syncthreads();
    const float mean = (red[0]+red[1]+red[2]+red[3]+red[4]+red[5]+red[6]+red[7]) * (1.f / D_);
    __syncthreads();
    const float v = y - mean;
    float vs = wave_sum64(v * v);
    if ((t & 63) == 0) red[t >> 6] = vs;
    __syncthreads();
    const float inv = rsqrtf((red[0]+red[1]+red[2]+red[3]+red[4]+red[5]+red[6]+red[7]) * (1.f / D_) + 1e-5f);
    const float p = fmaxf(fmaf(v * inv, lg[m * D_ + t], lb[m * D_ + t]), 0.f);
    ps[t] = p;
    __syncthreads();

    // ---- MLP1: wave w owns rows w*16 .. w*16+15 (512-length dots) ----
    {
        const float4* pv = (const float4*)ps;
        const float4 pa = pv[l];
        const float4 pbv = pv[64 + l];
        const float* w1base = W1 + (size_t)m * H4 * D_;
#pragma unroll 2
        for (int rr = 0; rr < 16; ++rr) {
            const int r = (w << 4) + rr;
            const float4* wr = (const float4*)(w1base + (size_t)r * D_);
            const float4 wa = wr[l];
            const float4 wb = wr[64 + l];
            float acc;
            acc = wa.x * pa.x;            acc = fmaf(wa.y, pa.y, acc);
            acc = fmaf(wa.z, pa.z, acc);  acc = fmaf(wa.w, pa.w, acc);
            acc = fmaf(wb.x, pbv.x, acc); acc = fmaf(wb.y, pbv.y, acc);
            acc = fmaf(wb.z, pbv.z, acc); acc = fmaf(wb.w, pbv.w, acc);
            acc = wave_sum64(acc);
            if (l == 0) hs[r] = fmaxf(acc + b1[m * H4 + r], 0.f);
        }
    }
    __syncthreads();

    // ---- MLP2: half-wave per row; wave w owns rows w*64 .. w*64+63.
    //      One wave-load = rows (r, r+1) = contiguous 1KB of W2. ----
    {
        const float4* hv = (const float4*)hs;     // 32 float4
        const float4 hc = hv[l & 31];
        const int half = l >> 5;
        const float* w2base = W2 + (size_t)m * D_ * H4;
#pragma unroll 2
        for (int s2 = 0; s2 < 32; ++s2) {
            const int r = (w << 6) + (s2 << 1) + half;
            const float4* wr = (const float4*)(w2base + (size_t)r * H4);
            const float4 w4 = wr[l & 31];
            float acc;
            acc = w4.x * hc.x;            acc = fmaf(w4.y, hc.y, acc);
            acc = fmaf(w4.z, hc.z, acc);  acc = fmaf(w4.w, hc.w, acc);
            acc = half_sum32(acc);
            if ((l & 31) == 0) ys[r] = acc;       // ys reused for a2
        }
    }
    __syncthreads();

    // ---- sigmoid gate, wf, Ssum ----
    const float cw = sigmoidf(ys[t] + b2[m * D_ + t]);
    const float wv = p * cw;
    wf[(size_t)(m * B_ + b) * D_ + t] = wv;

    float tot = wave_sum64(wv);
    if ((t & 63) == 0) red[t >> 6] = tot;
    __syncthreads();
    if (t == 0)
        Ssum[m * B_ + b] = red[0]+red[1]+red[2]+red[3]+red[4]+red[5]+red[6]+red[7];

    if (blockIdx.x == 0 && t == 0) {
        const float g01 = sigmoidf(gamma[1]), g02 = sigmoidf(gamma[2]);
        const float g10 = sigmoidf(gamma[3]), g12 = sigmoidf(gamma[5]);
        const float g20 = sigmoidf(gamma[6]), g21 = sigmoidf(gamma[7]);
        const float s0 = 0.5f * (g01 + g02);
        const float s1 = 0.5f * (g10 + g12);
        const float s2 = 0.5f * (g20 + g21);
        const float mx = fmaxf(s0, fmaxf(s1, s2));
        const float e0 = __expf(s0 - mx), e1 = __expf(s1 - mx), e2 = __expf(s2 - mx);
        const float den = e0 + e1 + e2;
        out[BD + 0] = e0 / den;
        out[BD + 1] = e1 / den;
        out[BD + 2] = e2 / den;
    }
}

// ---------------------------------------------------------------------------
// k_hist: history matrices, TRANSPOSED HT[i][e][d] pre-scaled by LOG2E.
// grid = 384 blocks: block=(i, e-quad), thread = d & d+256.
// ---------------------------------------------------------------------------
__global__ __launch_bounds__(256) void k_hist(
    const float* __restrict__ wf, const float* __restrict__ cons,
    float* __restrict__ HT)
{
    const int t  = threadIdx.x;
    const int i  = blockIdx.x >> 7;         // 128 blocks per mode
    const int e0 = (blockIdx.x & 127) << 2;
    const int j  = (i == 0) ? 1 : 0;
    const float c = cons[i];
    const float* wfi = wf + (size_t)i * BD;
    const float* wfj = wf + (size_t)j * BD;

    float h0[4] = {0.f, 0.f, 0.f, 0.f};
    float h1[4] = {0.f, 0.f, 0.f, 0.f};
#pragma unroll 2
    for (int b = 0; b < B_; ++b) {
        const float a0 = wfi[b * D_ + t]       * INVSCALE;
        const float a1 = wfi[b * D_ + t + 256] * INVSCALE;
        const float4 u4 = *(const float4*)(wfj + b * D_ + e0);
        const float uu[4] = {u4.x, u4.y, u4.z, u4.w};
#pragma unroll
        for (int k = 0; k < 4; ++k) {
            float tt = a0 * uu[k]; float mm = fminf(tt, c);
            h0[k] = fmaf(0.8f, mm, fmaf(0.2f, tt, h0[k]));
            tt = a1 * uu[k]; mm = fminf(tt, c);
            h1[k] = fmaf(0.8f, mm, fmaf(0.2f, tt, h1[k]));
        }
    }
    const float hsc = LOG2E / (float)(B_ * HIST_);
    float* r0 = HT + ((size_t)(i << 9) + e0) * D_;
#pragma unroll
    for (int k = 0; k < 4; ++k) {
        r0[(size_t)k * D_ + t]       = h0[k] * hsc;
        r0[(size_t)k * D_ + t + 256] = h1[k] * hsc;
    }
}

// ---------------------------------------------------------------------------
// k_pass: all 6 (i,j) softmax-dot passes per block, 4 batches per block.
// grid = 256 blocks: block=(b-quad, 32-d chunk), 256 thr = 32 d x 8 e-secs.
// Single non-atomic store: out[b,d] = sum(pv)/6 + (wf0+wf1+wf2)/3.
// ---------------------------------------------------------------------------
__global__ __launch_bounds__(256) void k_pass(
    const float* __restrict__ wf, const float* __restrict__ cons,
    const float* __restrict__ gamma, const float* __restrict__ mbias,
    const float* __restrict__ HT, const float* __restrict__ Ssum,
    float* __restrict__ out)
{
    const int bg   = blockIdx.x >> 4;       // 0..15 (b-quad)
    const int dc   = blockIdx.x & 15;
    const int b0   = bg << 2;
    const int t    = threadIdx.x;
    const int ln   = t & 31;
    const int d    = (dc << 5) + ln;
    const int esec = t >> 5;                // 0..7, 64 e's each

    __shared__ __align__(16) float4 part[4][256];
    float oacc = 0.f;                        // used by t<128

#pragma unroll
    for (int i = 0; i < 3; ++i) {
        const int jA = (i == 0) ? 1 : 0;
        const int jB = (i == 2) ? 1 : 2;
        const float c08 = cons[i] * (0.8f * LOG2E);
        const float cl  = cons[i] * LOG2E;

        float a08[4], a02[4], aB[4];
        const float* uA[4];
        const float* uB[4];
#pragma unroll
        for (int bb = 0; bb < 4; ++bb) {
            const float a = wf[(size_t)i * BD + (b0 + bb) * D_ + d];
            a08[bb] = a * (0.8f * INVSCALE * LOG2E);
            a02[bb] = a * (0.2f * INVSCALE * LOG2E);
            aB[bb]  = a * (INVSCALE * LOG2E);
            uA[bb] = wf + (size_t)jA * BD + (b0 + bb) * D_ + (esec << 6);
            uB[bb] = wf + (size_t)jB * BD + (b0 + bb) * D_ + (esec << 6);
        }
        const float* hp = HT + ((size_t)(i << 9) + (esec << 6)) * D_ + d;

        float sA[4] = {0.f, 0.f, 0.f, 0.f}, dA[4] = {0.f, 0.f, 0.f, 0.f};
        float sB[4] = {0.f, 0.f, 0.f, 0.f}, dB[4] = {0.f, 0.f, 0.f, 0.f};
#pragma unroll 2
        for (int e = 0; e < 64; e += 4) {
            float hh[4];
#pragma unroll
            for (int k = 0; k < 4; ++k) hh[k] = hp[(size_t)(e + k) * D_];
#pragma unroll
            for (int bb = 0; bb < 4; ++bb) {
                const float4 uA4 = *(const float4*)(uA[bb] + e);
                const float4 uB4 = *(const float4*)(uB[bb] + e);
                const float ua[4] = {uA4.x, uA4.y, uA4.z, uA4.w};
                const float ub[4] = {uB4.x, uB4.y, uB4.z, uB4.w};
#pragma unroll
                for (int k = 0; k < 4; ++k) {
                    // pass A (hist = 0): f = min(a08*u, c08) + a02*u
                    const float v1 = a08[bb] * ua[k];
                    const float v2 = fminf(v1, c08);
                    const float fA = fmaf(a02[bb], ua[k], v2);
                    const float pA = __builtin_amdgcn_exp2f(fA);
                    sA[bb] += pA;
                    dA[bb] = fmaf(pA, ua[k], dA[bb]);
                    // pass B: f = 0.8*(h + clip(a*u - h)) + 0.2*a*u
                    const float tt = aB[bb] * ub[k];
                    const float df = tt - hh[k];
                    const float mm = fminf(fmaxf(df, -cl), cl);
                    const float fB = fmaf(0.8f, hh[k] + mm, 0.2f * tt);
                    const float pB = __builtin_amdgcn_exp2f(fB);
                    sB[bb] += pB;
                    dB[bb] = fmaf(pB, ub[k], dB[bb]);
                }
            }
        }

#pragma unroll
        for (int bb = 0; bb < 4; ++bb)
            part[bb][t] = make_float4(sA[bb], dA[bb], sB[bb], dB[bb]);
        __syncthreads();
        if (t < 128) {
            const int bb = t >> 5;
            const int l  = t & 31;
            float SsA = 0.f, SdA = 0.f, SsB = 0.f, SdB = 0.f;
#pragma unroll
            for (int k = 0; k < 8; ++k) {
                const float4 pp = part[bb][l + (k << 5)];
                SsA += pp.x; SdA += pp.y; SsB += pp.z; SdB += pp.w;
            }
            const float gA = sigmoidf(gamma[i * 3 + jA]);
            const float gB = sigmoidf(gamma[i * 3 + jB]);
            oacc += gA * (SdA / SsA + mbias[i * 3 + jA] * Ssum[jA * B_ + b0 + bb]);
            oacc += gB * (SdB / SsB + mbias[i * 3 + jB] * Ssum[jB * B_ + b0 + bb]);
        }
        __syncthreads();                      // protect part reuse next i
    }

    if (t < 128) {
        const int bb = t >> 5;
        const int l  = t & 31;
        const int od = (dc << 5) + l;
        const float w0 = wf[(size_t)0 * BD + (b0 + bb) * D_ + od];
        const float w1 = wf[(size_t)1 * BD + (b0 + bb) * D_ + od];
        const float w2 = wf[(size_t)2 * BD + (b0 + bb) * D_ + od];
        out[(b0 + bb) * D_ + od] = oacc * (1.f / 6.f) + (w0 + w1 + w2) * (1.f / 3.f);
    }
}

// ---------------------------------------------------------------------------
extern "C" void kernel_launch(void* const* d_in, const int* in_sizes, int n_in,
                              void* d_out, int out_size, void* d_ws, size_t ws_size,
                              hipStream_t stream) {
    const float* x    = (const float*)d_in[0];
    const float* pW   = (const float*)d_in[1];
    const float* pb   = (const float*)d_in[2];
    const float* lg   = (const float*)d_in[3];
    const float* lb   = (const float*)d_in[4];
    const float* W1   = (const float*)d_in[5];
    const float* b1   = (const float*)d_in[6];
    const float* W2   = (const float*)d_in[7];
    const float* b2   = (const float*)d_in[8];
    const float* gamma= (const float*)d_in[9];
    const float* mb   = (const float*)d_in[10];
    const float* cons = (const float*)d_in[11];
    float* out = (float*)d_out;

    float* ws   = (float*)d_ws;
    float* wf   = ws;                 // 98304 floats
    float* Ssum = ws + 98304;         // 192
    float* HT   = ws + 98496;         // 786432 (HT[i][e][d], *LOG2E)

    k_projln<<<dim3(M_ * B_), dim3(512), 0, stream>>>(x, pW, pb, lg, lb, W1, b1, W2, b2, gamma, wf, Ssum, out);
    k_hist  <<<dim3(384),     dim3(256), 0, stream>>>(wf, cons, HT);
    k_pass  <<<dim3(256),     dim3(256), 0, stream>>>(wf, cons, gamma, mb, HT, Ssum, out);
}

// Round 9
// 150.674 us; speedup vs baseline: 1.5910x; 1.3150x over previous
//
#include <hip/hip_runtime.h>
#include <math.h>

#define M_ 3
#define B_ 64
#define D_ 512
#define H4 128     // D/4
#define HIST_ 5
#define BD (B_ * D_)        // 32768
#define INVSCALE 0.04419417382415922f   // 1/sqrt(512)
#define LOG2E 1.4426950408889634f

__device__ __forceinline__ float wave_sum64(float v) {
#pragma unroll
    for (int o = 32; o >= 1; o >>= 1) v += __shfl_xor(v, o, 64);
    return v;
}

__device__ __forceinline__ float sigmoidf(float x) {
    return 1.0f / (1.0f + __expf(-x));
}

// ---------------------------------------------------------------------------
// k_proj v4: partial GEMM ypart[m,b,kq,d] = sum_{k in kq} x[m,b,k]*W[m,d,k].
// R0's proven shape, b-QUAD staging: block = (m, kq, dh, b-quad), 256 thr,
// thread = d. W slice (256 d x 128 k) re-read 16x instead of 32x -> grid W
// demand 96 -> 48 MB (stage is L2-traffic-bound at ~4.5 TB/s; R5-R8
// falsified latency/divergence theories). xs[4][32] float4 read broadcast.
// Per-(b,d,kq) k-summation order identical to R0 -> bit-identical ypart.
// grid = 384 blocks. Blocks 0..127 zero out[0..BD) (stream order => lands
// before lnmlp's atomics). Block 0 writes attention weights.
// ---------------------------------------------------------------------------
__global__ __launch_bounds__(256) void k_proj(
    const float* __restrict__ x, const float* __restrict__ pW,
    const float* __restrict__ gamma, float* __restrict__ ypart,
    float* __restrict__ out)
{
    const int m   = blockIdx.x >> 7;       // 0..2
    const int r   = blockIdx.x & 127;
    const int kq  = r >> 5;                // 0..3
    const int rem = r & 31;
    const int dh  = rem >> 4;              // 0..1
    const int bq  = rem & 15;              // 0..15
    const int b0  = bq << 2;
    const int t   = threadIdx.x;
    const int d   = (dh << 8) + t;

    if (blockIdx.x < 128)
        out[(blockIdx.x << 8) + t] = 0.f;

    __shared__ __align__(16) float4 xs[4][32];
    if (t < 128) {
        const int rr = t >> 5, cc = t & 31;
        xs[rr][cc] = ((const float4*)(x + (size_t)(m * B_ + b0 + rr) * D_ + kq * 128))[cc];
    }
    __syncthreads();

    const float4* wr = (const float4*)(pW + (size_t)m * D_ * D_ + (size_t)d * D_ + kq * 128);
    float acc0 = 0.f, acc1 = 0.f, acc2 = 0.f, acc3 = 0.f;
#pragma unroll
    for (int k = 0; k < 32; ++k) {
        const float4 w = wr[k];
        const float4 a0 = xs[0][k];
        const float4 a1 = xs[1][k];
        const float4 a2 = xs[2][k];
        const float4 a3 = xs[3][k];
        acc0 = fmaf(w.x, a0.x, acc0); acc0 = fmaf(w.y, a0.y, acc0);
        acc0 = fmaf(w.z, a0.z, acc0); acc0 = fmaf(w.w, a0.w, acc0);
        acc1 = fmaf(w.x, a1.x, acc1); acc1 = fmaf(w.y, a1.y, acc1);
        acc1 = fmaf(w.z, a1.z, acc1); acc1 = fmaf(w.w, a1.w, acc1);
        acc2 = fmaf(w.x, a2.x, acc2); acc2 = fmaf(w.y, a2.y, acc2);
        acc2 = fmaf(w.z, a2.z, acc2); acc2 = fmaf(w.w, a2.w, acc2);
        acc3 = fmaf(w.x, a3.x, acc3); acc3 = fmaf(w.y, a3.y, acc3);
        acc3 = fmaf(w.z, a3.z, acc3); acc3 = fmaf(w.w, a3.w, acc3);
    }
    const size_t idx0 = (size_t)(m * B_ + b0) * 2048 + kq * 512 + d;
    ypart[idx0]        = acc0;
    ypart[idx0 + 2048] = acc1;
    ypart[idx0 + 4096] = acc2;
    ypart[idx0 + 6144] = acc3;

    if (blockIdx.x == 0 && t == 0) {
        const float g01 = sigmoidf(gamma[1]), g02 = sigmoidf(gamma[2]);
        const float g10 = sigmoidf(gamma[3]), g12 = sigmoidf(gamma[5]);
        const float g20 = sigmoidf(gamma[6]), g21 = sigmoidf(gamma[7]);
        const float s0 = 0.5f * (g01 + g02);
        const float s1 = 0.5f * (g10 + g12);
        const float s2 = 0.5f * (g20 + g21);
        const float mx = fmaxf(s0, fmaxf(s1, s2));
        const float e0 = __expf(s0 - mx), e1 = __expf(s1 - mx), e2 = __expf(s2 - mx);
        const float den = e0 + e1 + e2;
        out[BD + 0] = e0 / den;
        out[BD + 1] = e1 / den;
        out[BD + 2] = e2 / den;
    }
}

// ---------------------------------------------------------------------------
// k_lnmlp: R0-proven. per (m,b) row — sum 4 ypart quarters + pb,
// LayerNorm+ReLU, MLP1 (4-way K-split), MLP2, wf = p*sigmoid, Ssum.
// Adds wf/3 into out. grid = 192 blocks, 512 threads (thread = d).
// ---------------------------------------------------------------------------
__global__ __launch_bounds__(512) void k_lnmlp(
    const float* __restrict__ ypart, const float* __restrict__ pb,
    const float* __restrict__ lg, const float* __restrict__ lb,
    const float* __restrict__ W1, const float* __restrict__ b1,
    const float* __restrict__ W2, const float* __restrict__ b2,
    float* __restrict__ wf, float* __restrict__ Ssum,
    float* __restrict__ out)
{
    const int m = blockIdx.x >> 6;
    const int b = blockIdx.x & 63;
    const int t = threadIdx.x;
    __shared__ __align__(16) float ps[D_];
    __shared__ __align__(16) float hs[H4];
    __shared__ __align__(16) float hpart[512];
    __shared__ float red[8];

    const size_t rbase = (size_t)(m * B_ + b) * 2048;
    const float y = ypart[rbase + t] + ypart[rbase + 512 + t]
                  + ypart[rbase + 1024 + t] + ypart[rbase + 1536 + t]
                  + pb[m * D_ + t];

    float s = wave_sum64(y);
    if ((t & 63) == 0) red[t >> 6] = s;
    __syncthreads();
    const float mean = (red[0]+red[1]+red[2]+red[3]+red[4]+red[5]+red[6]+red[7]) * (1.f / D_);
    __syncthreads();
    const float v = y - mean;
    float vs = wave_sum64(v * v);
    if ((t & 63) == 0) red[t >> 6] = vs;
    __syncthreads();
    const float inv = rsqrtf((red[0]+red[1]+red[2]+red[3]+red[4]+red[5]+red[6]+red[7]) * (1.f / D_) + 1e-5f);
    const float p = fmaxf(fmaf(v * inv, lg[m * D_ + t], lb[m * D_ + t]), 0.f);
    ps[t] = p;
    __syncthreads();

    // MLP1: thread -> (r = t&127, seg = t>>7)
    {
        const int r = t & 127, seg = t >> 7;
        const float4* w1 = (const float4*)(W1 + ((size_t)m * H4 + r) * D_) + (seg << 5);
        const float4* pv = (const float4*)ps + (seg << 5);
        float a1 = 0.f;
#pragma unroll
        for (int k = 0; k < 32; ++k) {
            const float4 w = w1[k], pp = pv[k];
            a1 = fmaf(w.x, pp.x, a1); a1 = fmaf(w.y, pp.y, a1);
            a1 = fmaf(w.z, pp.z, a1); a1 = fmaf(w.w, pp.w, a1);
        }
        hpart[t] = a1;
    }
    __syncthreads();
    if (t < H4)
        hs[t] = fmaxf(hpart[t] + hpart[t + 128] + hpart[t + 256] + hpart[t + 384]
                      + b1[m * H4 + t], 0.f);
    __syncthreads();

    // MLP2
    const float4* w2 = (const float4*)(W2 + ((size_t)m * D_ + t) * H4);
    const float4* hv = (const float4*)hs;
    float a2 = 0.f;
#pragma unroll
    for (int k = 0; k < H4 / 4; ++k) {
        const float4 w = w2[k], hh = hv[k];
        a2 = fmaf(w.x, hh.x, a2); a2 = fmaf(w.y, hh.y, a2);
        a2 = fmaf(w.z, hh.z, a2); a2 = fmaf(w.w, hh.w, a2);
    }
    const float cw = sigmoidf(a2 + b2[m * D_ + t]);
    const float wv = p * cw;
    wf[(size_t)(m * B_ + b) * D_ + t] = wv;
    atomicAdd(&out[b * D_ + t], wv * (1.f / 3.f));

    float tot = wave_sum64(wv);
    if ((t & 63) == 0) red[t >> 6] = tot;
    __syncthreads();
    if (t == 0)
        Ssum[m * B_ + b] = red[0]+red[1]+red[2]+red[3]+red[4]+red[5]+red[6]+red[7];
}

// ---------------------------------------------------------------------------
// k_fuseAH: R1-proven batch-blocked fusion.
//  Blocks [0,768): pass A (hist=0), 4 batches per block.
//  Blocks [768,1152): history, TRANSPOSED HT[i][e][d] pre-scaled by LOG2E,
//  4 e's per block.
// ---------------------------------------------------------------------------
__global__ __launch_bounds__(256) void k_fuseAH(
    const float* __restrict__ wf, const float* __restrict__ constraint,
    const float* __restrict__ gamma, const float* __restrict__ mbias,
    const float* __restrict__ Ssum, float* __restrict__ HT,
    float* __restrict__ out)
{
    const int t = threadIdx.x;

    if (blockIdx.x < 768) {
        // ---- pass A, 4 batches per block ----
        const int i    = blockIdx.x >> 8;          // 256 blocks per mode
        const int rem  = blockIdx.x & 255;
        const int b0   = (rem >> 4) << 2;          // batch group base
        const int dc   = rem & 15;
        const int ln   = t & 31;
        const int d    = (dc << 5) + ln;
        const int esec = t >> 5;                   // 0..7, 64 e's each
        const int jA   = (i == 0) ? 1 : 0;

        const float c08 = constraint[i] * (0.8f * LOG2E);
        float a08[4], a02[4];
        const float* uAp[4];
#pragma unroll
        for (int bb = 0; bb < 4; ++bb) {
            const float a = wf[(size_t)i * BD + (b0 + bb) * D_ + d];
            a08[bb] = a * (0.8f * INVSCALE * LOG2E);
            a02[bb] = a * (0.2f * INVSCALE * LOG2E);
            uAp[bb] = wf + (size_t)jA * BD + (b0 + bb) * D_ + (esec << 6);
        }

        float sA[4] = {0.f, 0.f, 0.f, 0.f};
        float dA[4] = {0.f, 0.f, 0.f, 0.f};
#pragma unroll 2
        for (int e = 0; e < 64; e += 4) {
#pragma unroll
            for (int bb = 0; bb < 4; ++bb) {
                const float4 u4 = *(const float4*)(uAp[bb] + e);
                const float uu[4] = {u4.x, u4.y, u4.z, u4.w};
#pragma unroll
                for (int k = 0; k < 4; ++k) {
                    const float v1 = a08[bb] * uu[k];
                    const float v2 = fminf(v1, c08);
                    const float f  = fmaf(a02[bb], uu[k], v2);
                    const float p  = __builtin_amdgcn_exp2f(f);
                    sA[bb] += p;
                    dA[bb] = fmaf(p, uu[k], dA[bb]);
                }
            }
        }

        __shared__ __align__(8) float2 part[4][256];
#pragma unroll
        for (int bb = 0; bb < 4; ++bb)
            part[bb][t] = make_float2(sA[bb], dA[bb]);
        __syncthreads();
        if (t < 128) {
            const int bb = t >> 5;
            const int l  = t & 31;
            float Ss = 0.f, Sd = 0.f;
#pragma unroll
            for (int k = 0; k < 8; ++k) {
                const float2 pp = part[bb][l + (k << 5)];
                Ss += pp.x; Sd += pp.y;
            }
            const float gA = sigmoidf(gamma[i * 3 + jA]);
            const float pv = gA * (Sd / Ss + mbias[i * 3 + jA] * Ssum[jA * B_ + b0 + bb]);
            atomicAdd(&out[(b0 + bb) * D_ + (dc << 5) + l], pv * (1.f / 6.f));
        }
        return;
    }

    // ---- history (HT[i][e][d], thread = d & d+256; 4 e's per block) ----
    const int hb = blockIdx.x - 768;
    const int i  = hb >> 7;                 // 128 blocks per mode
    const int e0 = (hb & 127) << 2;
    const int j  = (i == 0) ? 1 : 0;
    const float c = constraint[i];
    const float* wfi = wf + (size_t)i * BD;
    const float* wfj = wf + (size_t)j * BD;

    float h0[4] = {0.f, 0.f, 0.f, 0.f};
    float h1[4] = {0.f, 0.f, 0.f, 0.f};
#pragma unroll 2
    for (int b = 0; b < B_; ++b) {
        const float a0 = wfi[b * D_ + t]       * INVSCALE;
        const float a1 = wfi[b * D_ + t + 256] * INVSCALE;
        const float4 u4 = *(const float4*)(wfj + b * D_ + e0);
        const float uu[4] = {u4.x, u4.y, u4.z, u4.w};
#pragma unroll
        for (int k = 0; k < 4; ++k) {
            float tt = a0 * uu[k]; float mm = fminf(tt, c);
            h0[k] = fmaf(0.8f, mm, fmaf(0.2f, tt, h0[k]));
            tt = a1 * uu[k]; mm = fminf(tt, c);
            h1[k] = fmaf(0.8f, mm, fmaf(0.2f, tt, h1[k]));
        }
    }
    const float hsc = LOG2E / (float)(B_ * HIST_);
    float* r0 = HT + ((size_t)(i << 9) + e0) * D_;
#pragma unroll
    for (int k = 0; k < 4; ++k) {
        r0[(size_t)k * D_ + t]       = h0[k] * hsc;
        r0[(size_t)k * D_ + t + 256] = h1[k] * hsc;
    }
}

// ---------------------------------------------------------------------------
// k_passB: R1-proven. second-j softmax-dot with hist = HT, 4 batches/block.
// grid = 768 blocks.
// ---------------------------------------------------------------------------
__global__ __launch_bounds__(256) void k_passB(
    const float* __restrict__ wf, const float* __restrict__ constraint,
    const float* __restrict__ gamma, const float* __restrict__ mbias,
    const float* __restrict__ HT, const float* __restrict__ Ssum,
    float* __restrict__ out)
{
    const int i    = blockIdx.x >> 8;
    const int rem  = blockIdx.x & 255;
    const int b0   = (rem >> 4) << 2;
    const int dc   = rem & 15;
    const int t    = threadIdx.x;
    const int ln   = t & 31;
    const int d    = (dc << 5) + ln;
    const int esec = t >> 5;                // 0..7, 64 e's each
    const int jB   = (i == 2) ? 1 : 2;

    const float cl = constraint[i] * LOG2E;
    float a[4];
    const float* uBp[4];
#pragma unroll
    for (int bb = 0; bb < 4; ++bb) {
        a[bb]  = wf[(size_t)i * BD + (b0 + bb) * D_ + d] * (INVSCALE * LOG2E);
        uBp[bb] = wf + (size_t)jB * BD + (b0 + bb) * D_ + (esec << 6);
    }
    const float* hp = HT + ((size_t)(i << 9) + (esec << 6)) * D_ + d;

    float sB[4] = {0.f, 0.f, 0.f, 0.f};
    float dB[4] = {0.f, 0.f, 0.f, 0.f};
#pragma unroll 2
    for (int e = 0; e < 64; e += 4) {
        float hh[4];
#pragma unroll
        for (int k = 0; k < 4; ++k) hh[k] = hp[(size_t)(e + k) * D_];
#pragma unroll
        for (int bb = 0; bb < 4; ++bb) {
            const float4 u4 = *(const float4*)(uBp[bb] + e);
            const float uu[4] = {u4.x, u4.y, u4.z, u4.w};
#pragma unroll
            for (int k = 0; k < 4; ++k) {
                const float tt = a[bb] * uu[k];
                const float df = tt - hh[k];
                const float mm = fminf(fmaxf(df, -cl), cl);
                const float f  = fmaf(0.8f, hh[k] + mm, 0.2f * tt);
                const float p  = __builtin_amdgcn_exp2f(f);
                sB[bb] += p;
                dB[bb] = fmaf(p, uu[k], dB[bb]);
            }
        }
    }

    __shared__ __align__(8) float2 part[4][256];
#pragma unroll
    for (int bb = 0; bb < 4; ++bb)
        part[bb][t] = make_float2(sB[bb], dB[bb]);
    __syncthreads();
    if (t < 128) {
        const int bb = t >> 5;
        const int l  = t & 31;
        float Ss = 0.f, Sd = 0.f;
#pragma unroll
        for (int k = 0; k < 8; ++k) {
            const float2 pp = part[bb][l + (k << 5)];
            Ss += pp.x; Sd += pp.y;
        }
        const float gB = sigmoidf(gamma[i * 3 + jB]);
        const float pv = gB * (Sd / Ss + mbias[i * 3 + jB] * Ssum[jB * B_ + b0 + bb]);
        atomicAdd(&out[(b0 + bb) * D_ + (dc << 5) + l], pv * (1.f / 6.f));
    }
}

// ---------------------------------------------------------------------------
extern "C" void kernel_launch(void* const* d_in, const int* in_sizes, int n_in,
                              void* d_out, int out_size, void* d_ws, size_t ws_size,
                              hipStream_t stream) {
    const float* x    = (const float*)d_in[0];
    const float* pW   = (const float*)d_in[1];
    const float* pb   = (const float*)d_in[2];
    const float* lg   = (const float*)d_in[3];
    const float* lb   = (const float*)d_in[4];
    const float* W1   = (const float*)d_in[5];
    const float* b1   = (const float*)d_in[6];
    const float* W2   = (const float*)d_in[7];
    const float* b2   = (const float*)d_in[8];
    const float* gamma= (const float*)d_in[9];
    const float* mb   = (const float*)d_in[10];
    const float* cons = (const float*)d_in[11];
    float* out = (float*)d_out;

    float* ws    = (float*)d_ws;
    float* wf    = ws;                 // 98304 floats
    float* Ssum  = ws + 98304;         // 192
    float* HT    = ws + 98496;         // 786432 (HT[i][e][d], *LOG2E)
    float* ypart = ws + 884928;        // 393216

    k_proj  <<<dim3(384),     dim3(256), 0, stream>>>(x, pW, gamma, ypart, out);
    k_lnmlp <<<dim3(M_ * B_), dim3(512), 0, stream>>>(ypart, pb, lg, lb, W1, b1, W2, b2, wf, Ssum, out);
    k_fuseAH<<<dim3(1152),    dim3(256), 0, stream>>>(wf, cons, gamma, mb, Ssum, HT, out);
    k_passB <<<dim3(768),     dim3(256), 0, stream>>>(wf, cons, gamma, mb, HT, Ssum, out);
}

// Round 10
// 150.563 us; speedup vs baseline: 1.5922x; 1.0007x over previous
//
#include <hip/hip_runtime.h>
#include <math.h>

#define M_ 3
#define B_ 64
#define D_ 512
#define H4 128     // D/4
#define HIST_ 5
#define BD (B_ * D_)        // 32768
#define INVSCALE 0.04419417382415922f   // 1/sqrt(512)
#define LOG2E 1.4426950408889634f

__device__ __forceinline__ float wave_sum64(float v) {
#pragma unroll
    for (int o = 32; o >= 1; o >>= 1) v += __shfl_xor(v, o, 64);
    return v;
}

__device__ __forceinline__ float sigmoidf(float x) {
    return 1.0f / (1.0f + __expf(-x));
}

// ---------------------------------------------------------------------------
// k_proj v4 (R9-proven): partial GEMM ypart[m,b,kq,d], b-quad staging.
// grid = 384 blocks. Blocks 0..127 zero out[0..BD). Block 0 writes attn
// weights. Per-(b,d,kq) k-summation order identical to R0.
// ---------------------------------------------------------------------------
__global__ __launch_bounds__(256) void k_proj(
    const float* __restrict__ x, const float* __restrict__ pW,
    const float* __restrict__ gamma, float* __restrict__ ypart,
    float* __restrict__ out)
{
    const int m   = blockIdx.x >> 7;       // 0..2
    const int r   = blockIdx.x & 127;
    const int kq  = r >> 5;                // 0..3
    const int rem = r & 31;
    const int dh  = rem >> 4;              // 0..1
    const int bq  = rem & 15;              // 0..15
    const int b0  = bq << 2;
    const int t   = threadIdx.x;
    const int d   = (dh << 8) + t;

    if (blockIdx.x < 128)
        out[(blockIdx.x << 8) + t] = 0.f;

    __shared__ __align__(16) float4 xs[4][32];
    if (t < 128) {
        const int rr = t >> 5, cc = t & 31;
        xs[rr][cc] = ((const float4*)(x + (size_t)(m * B_ + b0 + rr) * D_ + kq * 128))[cc];
    }
    __syncthreads();

    const float4* wr = (const float4*)(pW + (size_t)m * D_ * D_ + (size_t)d * D_ + kq * 128);
    float acc0 = 0.f, acc1 = 0.f, acc2 = 0.f, acc3 = 0.f;
#pragma unroll
    for (int k = 0; k < 32; ++k) {
        const float4 w = wr[k];
        const float4 a0 = xs[0][k];
        const float4 a1 = xs[1][k];
        const float4 a2 = xs[2][k];
        const float4 a3 = xs[3][k];
        acc0 = fmaf(w.x, a0.x, acc0); acc0 = fmaf(w.y, a0.y, acc0);
        acc0 = fmaf(w.z, a0.z, acc0); acc0 = fmaf(w.w, a0.w, acc0);
        acc1 = fmaf(w.x, a1.x, acc1); acc1 = fmaf(w.y, a1.y, acc1);
        acc1 = fmaf(w.z, a1.z, acc1); acc1 = fmaf(w.w, a1.w, acc1);
        acc2 = fmaf(w.x, a2.x, acc2); acc2 = fmaf(w.y, a2.y, acc2);
        acc2 = fmaf(w.z, a2.z, acc2); acc2 = fmaf(w.w, a2.w, acc2);
        acc3 = fmaf(w.x, a3.x, acc3); acc3 = fmaf(w.y, a3.y, acc3);
        acc3 = fmaf(w.z, a3.z, acc3); acc3 = fmaf(w.w, a3.w, acc3);
    }
    const size_t idx0 = (size_t)(m * B_ + b0) * 2048 + kq * 512 + d;
    ypart[idx0]        = acc0;
    ypart[idx0 + 2048] = acc1;
    ypart[idx0 + 4096] = acc2;
    ypart[idx0 + 6144] = acc3;

    if (blockIdx.x == 0 && t == 0) {
        const float g01 = sigmoidf(gamma[1]), g02 = sigmoidf(gamma[2]);
        const float g10 = sigmoidf(gamma[3]), g12 = sigmoidf(gamma[5]);
        const float g20 = sigmoidf(gamma[6]), g21 = sigmoidf(gamma[7]);
        const float s0 = 0.5f * (g01 + g02);
        const float s1 = 0.5f * (g10 + g12);
        const float s2 = 0.5f * (g20 + g21);
        const float mx = fmaxf(s0, fmaxf(s1, s2));
        const float e0 = __expf(s0 - mx), e1 = __expf(s1 - mx), e2 = __expf(s2 - mx);
        const float den = e0 + e1 + e2;
        out[BD + 0] = e0 / den;
        out[BD + 1] = e1 / den;
        out[BD + 2] = e2 / den;
    }
}

// ---------------------------------------------------------------------------
// k_lnmlp v2: batch-PAIR blocking. block = (m, b-pair), 96 blocks x 1024 thr
// (thread = (bb = t>>9, d = t&511)). W1/W2 float4s loaded once per block,
// used for BOTH batches -> W traffic 96 -> 48 MB (lnmlp was the largest
// remaining L2 consumer; ~3 TB/s aggregate observed R5/R8).
// Numerics: LN = R0's exact per-batch 8-wave tree (waves 0-7 bb0, 8-15 bb1);
// MLP1 = 8-seg x 64-dot order (R6-passed); MLP2 = kh-half split (R6-passed).
// ---------------------------------------------------------------------------
__global__ __launch_bounds__(1024) void k_lnmlp(
    const float* __restrict__ ypart, const float* __restrict__ pb,
    const float* __restrict__ lg, const float* __restrict__ lb,
    const float* __restrict__ W1, const float* __restrict__ b1,
    const float* __restrict__ W2, const float* __restrict__ b2,
    float* __restrict__ wf, float* __restrict__ Ssum,
    float* __restrict__ out)
{
    const int m  = blockIdx.x >> 5;      // 96 blocks: 32 b-pairs per mode
    const int bp = blockIdx.x & 31;
    const int b0 = bp << 1;
    const int t  = threadIdx.x;          // 0..1023
    const int bb = t >> 9;               // 0/1
    const int td = t & 511;              // d

    __shared__ __align__(16) float ps[2][D_];         // 4 KB
    __shared__ __align__(16) float hpart[2][1024];    // 8 KB
    __shared__ __align__(16) float hs[2][H4];         // 1 KB
    __shared__ __align__(16) float mpart[2][2][D_];   // 8 KB [kh][bb][d]
    __shared__ float red[2][8];

    const int b = b0 + bb;
    const size_t rbase = (size_t)(m * B_ + b) * 2048;
    const float y = ypart[rbase + td] + ypart[rbase + 512 + td]
                  + ypart[rbase + 1024 + td] + ypart[rbase + 1536 + td]
                  + pb[m * D_ + td];

    const int w8 = (t >> 6) & 7;         // wave index within bb-half
    float s = wave_sum64(y);
    if ((t & 63) == 0) red[bb][w8] = s;
    __syncthreads();
    const float mean = (red[bb][0]+red[bb][1]+red[bb][2]+red[bb][3]
                       +red[bb][4]+red[bb][5]+red[bb][6]+red[bb][7]) * (1.f / D_);
    __syncthreads();
    const float v = y - mean;
    float vs = wave_sum64(v * v);
    if ((t & 63) == 0) red[bb][w8] = vs;
    __syncthreads();
    const float inv = rsqrtf((red[bb][0]+red[bb][1]+red[bb][2]+red[bb][3]
                             +red[bb][4]+red[bb][5]+red[bb][6]+red[bb][7]) * (1.f / D_) + 1e-5f);
    const float p = fmaxf(fmaf(v * inv, lg[m * D_ + td], lb[m * D_ + td]), 0.f);
    ps[bb][td] = p;
    __syncthreads();

    // MLP1: thread -> (r = t&127, seg = t>>7, 8 segs); W1 read once, 2 batches
    {
        const int r = t & 127, seg = t >> 7;
        const float4* w1 = (const float4*)(W1 + ((size_t)m * H4 + r) * D_) + (seg << 4);
        const float4* p0 = (const float4*)ps[0] + (seg << 4);
        const float4* p1 = (const float4*)ps[1] + (seg << 4);
        float a10 = 0.f, a11 = 0.f;
#pragma unroll
        for (int k = 0; k < 16; ++k) {
            const float4 w = w1[k];
            const float4 q0 = p0[k], q1 = p1[k];
            a10 = fmaf(w.x, q0.x, a10); a10 = fmaf(w.y, q0.y, a10);
            a10 = fmaf(w.z, q0.z, a10); a10 = fmaf(w.w, q0.w, a10);
            a11 = fmaf(w.x, q1.x, a11); a11 = fmaf(w.y, q1.y, a11);
            a11 = fmaf(w.z, q1.z, a11); a11 = fmaf(w.w, q1.w, a11);
        }
        hpart[0][t] = a10;
        hpart[1][t] = a11;
    }
    __syncthreads();
    if (t < 256) {
        const int bh = t >> 7, r = t & 127;
        float h = hpart[bh][r];
#pragma unroll
        for (int seg = 1; seg < 8; ++seg) h += hpart[bh][(seg << 7) + r];
        hs[bh][r] = fmaxf(h + b1[m * H4 + r], 0.f);
    }
    __syncthreads();

    // MLP2: thread -> (kh = t>>9, d = td); W2 half-row read once, 2 batches
    {
        const int kh = t >> 9;
        const float4* w2 = (const float4*)(W2 + ((size_t)m * D_ + td) * H4) + (kh << 4);
        const float4* h0 = (const float4*)hs[0] + (kh << 4);
        const float4* h1 = (const float4*)hs[1] + (kh << 4);
        float a20 = 0.f, a21 = 0.f;
#pragma unroll
        for (int k = 0; k < 16; ++k) {
            const float4 w = w2[k];
            const float4 q0 = h0[k], q1 = h1[k];
            a20 = fmaf(w.x, q0.x, a20); a20 = fmaf(w.y, q0.y, a20);
            a20 = fmaf(w.z, q0.z, a20); a20 = fmaf(w.w, q0.w, a20);
            a21 = fmaf(w.x, q1.x, a21); a21 = fmaf(w.y, q1.y, a21);
            a21 = fmaf(w.z, q1.z, a21); a21 = fmaf(w.w, q1.w, a21);
        }
        mpart[kh][0][td] = a20;
        mpart[kh][1][td] = a21;
    }
    __syncthreads();

    // gate + wf + out + Ssum (thread = (bb, td) again)
    const float a2 = mpart[0][bb][td] + mpart[1][bb][td] + b2[m * D_ + td];
    const float cw = sigmoidf(a2);
    const float wv = p * cw;
    wf[(size_t)(m * B_ + b) * D_ + td] = wv;
    atomicAdd(&out[b * D_ + td], wv * (1.f / 3.f));

    float tot = wave_sum64(wv);
    if ((t & 63) == 0) red[bb][w8] = tot;
    __syncthreads();
    if ((t & 511) == 0)
        Ssum[m * B_ + b] = red[bb][0]+red[bb][1]+red[bb][2]+red[bb][3]
                          +red[bb][4]+red[bb][5]+red[bb][6]+red[bb][7];
}

// ---------------------------------------------------------------------------
// k_fuseAH (R1/R9-proven): pass A (4 batches/block) + history.
// ---------------------------------------------------------------------------
__global__ __launch_bounds__(256) void k_fuseAH(
    const float* __restrict__ wf, const float* __restrict__ constraint,
    const float* __restrict__ gamma, const float* __restrict__ mbias,
    const float* __restrict__ Ssum, float* __restrict__ HT,
    float* __restrict__ out)
{
    const int t = threadIdx.x;

    if (blockIdx.x < 768) {
        const int i    = blockIdx.x >> 8;
        const int rem  = blockIdx.x & 255;
        const int b0   = (rem >> 4) << 2;
        const int dc   = rem & 15;
        const int ln   = t & 31;
        const int d    = (dc << 5) + ln;
        const int esec = t >> 5;
        const int jA   = (i == 0) ? 1 : 0;

        const float c08 = constraint[i] * (0.8f * LOG2E);
        float a08[4], a02[4];
        const float* uAp[4];
#pragma unroll
        for (int bb = 0; bb < 4; ++bb) {
            const float a = wf[(size_t)i * BD + (b0 + bb) * D_ + d];
            a08[bb] = a * (0.8f * INVSCALE * LOG2E);
            a02[bb] = a * (0.2f * INVSCALE * LOG2E);
            uAp[bb] = wf + (size_t)jA * BD + (b0 + bb) * D_ + (esec << 6);
        }

        float sA[4] = {0.f, 0.f, 0.f, 0.f};
        float dA[4] = {0.f, 0.f, 0.f, 0.f};
#pragma unroll 2
        for (int e = 0; e < 64; e += 4) {
#pragma unroll
            for (int bb = 0; bb < 4; ++bb) {
                const float4 u4 = *(const float4*)(uAp[bb] + e);
                const float uu[4] = {u4.x, u4.y, u4.z, u4.w};
#pragma unroll
                for (int k = 0; k < 4; ++k) {
                    const float v1 = a08[bb] * uu[k];
                    const float v2 = fminf(v1, c08);
                    const float f  = fmaf(a02[bb], uu[k], v2);
                    const float p  = __builtin_amdgcn_exp2f(f);
                    sA[bb] += p;
                    dA[bb] = fmaf(p, uu[k], dA[bb]);
                }
            }
        }

        __shared__ __align__(8) float2 part[4][256];
#pragma unroll
        for (int bb = 0; bb < 4; ++bb)
            part[bb][t] = make_float2(sA[bb], dA[bb]);
        __syncthreads();
        if (t < 128) {
            const int bb = t >> 5;
            const int l  = t & 31;
            float Ss = 0.f, Sd = 0.f;
#pragma unroll
            for (int k = 0; k < 8; ++k) {
                const float2 pp = part[bb][l + (k << 5)];
                Ss += pp.x; Sd += pp.y;
            }
            const float gA = sigmoidf(gamma[i * 3 + jA]);
            const float pv = gA * (Sd / Ss + mbias[i * 3 + jA] * Ssum[jA * B_ + b0 + bb]);
            atomicAdd(&out[(b0 + bb) * D_ + (dc << 5) + l], pv * (1.f / 6.f));
        }
        return;
    }

    const int hb = blockIdx.x - 768;
    const int i  = hb >> 7;
    const int e0 = (hb & 127) << 2;
    const int j  = (i == 0) ? 1 : 0;
    const float c = constraint[i];
    const float* wfi = wf + (size_t)i * BD;
    const float* wfj = wf + (size_t)j * BD;

    float h0[4] = {0.f, 0.f, 0.f, 0.f};
    float h1[4] = {0.f, 0.f, 0.f, 0.f};
#pragma unroll 2
    for (int b = 0; b < B_; ++b) {
        const float a0 = wfi[b * D_ + t]       * INVSCALE;
        const float a1 = wfi[b * D_ + t + 256] * INVSCALE;
        const float4 u4 = *(const float4*)(wfj + b * D_ + e0);
        const float uu[4] = {u4.x, u4.y, u4.z, u4.w};
#pragma unroll
        for (int k = 0; k < 4; ++k) {
            float tt = a0 * uu[k]; float mm = fminf(tt, c);
            h0[k] = fmaf(0.8f, mm, fmaf(0.2f, tt, h0[k]));
            tt = a1 * uu[k]; mm = fminf(tt, c);
            h1[k] = fmaf(0.8f, mm, fmaf(0.2f, tt, h1[k]));
        }
    }
    const float hsc = LOG2E / (float)(B_ * HIST_);
    float* r0 = HT + ((size_t)(i << 9) + e0) * D_;
#pragma unroll
    for (int k = 0; k < 4; ++k) {
        r0[(size_t)k * D_ + t]       = h0[k] * hsc;
        r0[(size_t)k * D_ + t + 256] = h1[k] * hsc;
    }
}

// ---------------------------------------------------------------------------
// k_passB (R1/R9-proven): second-j softmax-dot with hist = HT, 4 batches.
// ---------------------------------------------------------------------------
__global__ __launch_bounds__(256) void k_passB(
    const float* __restrict__ wf, const float* __restrict__ constraint,
    const float* __restrict__ gamma, const float* __restrict__ mbias,
    const float* __restrict__ HT, const float* __restrict__ Ssum,
    float* __restrict__ out)
{
    const int i    = blockIdx.x >> 8;
    const int rem  = blockIdx.x & 255;
    const int b0   = (rem >> 4) << 2;
    const int dc   = rem & 15;
    const int t    = threadIdx.x;
    const int ln   = t & 31;
    const int d    = (dc << 5) + ln;
    const int esec = t >> 5;
    const int jB   = (i == 2) ? 1 : 2;

    const float cl = constraint[i] * LOG2E;
    float a[4];
    const float* uBp[4];
#pragma unroll
    for (int bb = 0; bb < 4; ++bb) {
        a[bb]  = wf[(size_t)i * BD + (b0 + bb) * D_ + d] * (INVSCALE * LOG2E);
        uBp[bb] = wf + (size_t)jB * BD + (b0 + bb) * D_ + (esec << 6);
    }
    const float* hp = HT + ((size_t)(i << 9) + (esec << 6)) * D_ + d;

    float sB[4] = {0.f, 0.f, 0.f, 0.f};
    float dB[4] = {0.f, 0.f, 0.f, 0.f};
#pragma unroll 2
    for (int e = 0; e < 64; e += 4) {
        float hh[4];
#pragma unroll
        for (int k = 0; k < 4; ++k) hh[k] = hp[(size_t)(e + k) * D_];
#pragma unroll
        for (int bb = 0; bb < 4; ++bb) {
            const float4 u4 = *(const float4*)(uBp[bb] + e);
            const float uu[4] = {u4.x, u4.y, u4.z, u4.w};
#pragma unroll
            for (int k = 0; k < 4; ++k) {
                const float tt = a[bb] * uu[k];
                const float df = tt - hh[k];
                const float mm = fminf(fmaxf(df, -cl), cl);
                const float f  = fmaf(0.8f, hh[k] + mm, 0.2f * tt);
                const float p  = __builtin_amdgcn_exp2f(f);
                sB[bb] += p;
                dB[bb] = fmaf(p, uu[k], dB[bb]);
            }
        }
    }

    __shared__ __align__(8) float2 part[4][256];
#pragma unroll
    for (int bb = 0; bb < 4; ++bb)
        part[bb][t] = make_float2(sB[bb], dB[bb]);
    __syncthreads();
    if (t < 128) {
        const int bb = t >> 5;
        const int l  = t & 31;
        float Ss = 0.f, Sd = 0.f;
#pragma unroll
        for (int k = 0; k < 8; ++k) {
            const float2 pp = part[bb][l + (k << 5)];
            Ss += pp.x; Sd += pp.y;
        }
        const float gB = sigmoidf(gamma[i * 3 + jB]);
        const float pv = gB * (Sd / Ss + mbias[i * 3 + jB] * Ssum[jB * B_ + b0 + bb]);
        atomicAdd(&out[(b0 + bb) * D_ + (dc << 5) + l], pv * (1.f / 6.f));
    }
}

// ---------------------------------------------------------------------------
extern "C" void kernel_launch(void* const* d_in, const int* in_sizes, int n_in,
                              void* d_out, int out_size, void* d_ws, size_t ws_size,
                              hipStream_t stream) {
    const float* x    = (const float*)d_in[0];
    const float* pW   = (const float*)d_in[1];
    const float* pb   = (const float*)d_in[2];
    const float* lg   = (const float*)d_in[3];
    const float* lb   = (const float*)d_in[4];
    const float* W1   = (const float*)d_in[5];
    const float* b1   = (const float*)d_in[6];
    const float* W2   = (const float*)d_in[7];
    const float* b2   = (const float*)d_in[8];
    const float* gamma= (const float*)d_in[9];
    const float* mb   = (const float*)d_in[10];
    const float* cons = (const float*)d_in[11];
    float* out = (float*)d_out;

    float* ws    = (float*)d_ws;
    float* wf    = ws;                 // 98304 floats
    float* Ssum  = ws + 98304;         // 192
    float* HT    = ws + 98496;         // 786432 (HT[i][e][d], *LOG2E)
    float* ypart = ws + 884928;        // 393216

    k_proj  <<<dim3(384),  dim3(256),  0, stream>>>(x, pW, gamma, ypart, out);
    k_lnmlp <<<dim3(96),   dim3(1024), 0, stream>>>(ypart, pb, lg, lb, W1, b1, W2, b2, wf, Ssum, out);
    k_fuseAH<<<dim3(1152), dim3(256),  0, stream>>>(wf, cons, gamma, mb, Ssum, HT, out);
    k_passB <<<dim3(768),  dim3(256),  0, stream>>>(wf, cons, gamma, mb, HT, Ssum, out);
}